// Round 5
// baseline (413.379 us; speedup 1.0000x reference)
//
#include <hip/hip_runtime.h>
#include <hip/hip_bf16.h>
#include <cstdint>

#define BB 8
#define CC 16
#define DD 32
#define HH 112
#define WW 112
#define TT 16        // D_OUT
#define HID 256
#define OUTN 128
#define INSZ 784     // C*7*7
#define NCACHE 48    // whhP rows pinned in LDS (48*768*4 = 144 KB; +4 KB state = 148 KB — PROVEN)
#define NREG (128 - NCACHE)   // 80 rows held in per-thread registers across the t-loop

__device__ __forceinline__ float bf16lo(uint32_t u) { return __uint_as_float(u << 16); }
__device__ __forceinline__ float bf16hi(uint32_t u) { return __uint_as_float(u & 0xffff0000u); }
__device__ __forceinline__ float bf16s(uint16_t u)  { return __uint_as_float(((uint32_t)u) << 16); }

__device__ __forceinline__ uint16_t f32_to_bf16_rne(float f) {
    uint32_t u = __float_as_uint(f);
    return (uint16_t)((u + 0x7fffu + ((u >> 16) & 1u)) >> 16);
}

// ---------------------------------------------------------------------------
// Dtype detector (PROVEN): flag=1 -> float32, 0 -> bfloat16.
// ---------------------------------------------------------------------------
__global__ __launch_bounds__(256) void detect_kernel(const uint16_t* __restrict__ x,
                                                     int* __restrict__ flag) {
    __shared__ int cnt;
    if (threadIdx.x == 0) cnt = 0;
    __syncthreads();
    int local = 0;
    for (int i = threadIdx.x; i < 8192; i += 256) {
        uint32_t e = (x[i] >> 7) & 0xFFu;
        if (e == 0u || e >= 0x90u) local++;
    }
    atomicAdd(&cnt, local);
    __syncthreads();
    if (threadIdx.x == 0) *flag = (cnt > 400) ? 1 : 0;
}

// ---------------------------------------------------------------------------
// prep2: pool + W_ih transpose + W_hh pack + gi bias init in ONE launch.
// Flag is LOADED (detect already ran) — not re-detected per block (r2 lesson).
// blocks [0,2048): pool (long pole, scheduled first)
// blocks [2048,2204): wihT 64x64 tiled transpose (156)
// blocks [2204,2588): whhP bf16 pack (384)
// blocks [2588,2972): gi = b_ih init (384)
// ---------------------------------------------------------------------------
__global__ __launch_bounds__(256) void prep2_kernel(const void* __restrict__ xv,
                                                    float* __restrict__ seq,
                                                    const void* __restrict__ Wih,
                                                    float* __restrict__ wihT,
                                                    const void* __restrict__ Whh,
                                                    uint32_t* __restrict__ whhP,
                                                    const void* __restrict__ bih,
                                                    float* __restrict__ gi,
                                                    const int* __restrict__ flag) {
    const int isf32 = *flag;
    const int blk = blockIdx.x;
    const int tid = threadIdx.x;
    __shared__ float chunk[6272];             // pool buffer; reused as transpose tile
    if (blk < 2048) {
        // ---------------- pool: x -> seq (T,B,INSZ) f32, mean over 512 -------
        int t = blk & 15, c = (blk >> 4) & 15, b = blk >> 8;
        long base = (long)(((b * CC + c) * DD) + t * 2) * (HH * WW);
        float s = 0.0f;
        if (!isf32) {
            const uint4* p = reinterpret_cast<const uint4*>((const uint16_t*)xv + base);
            for (int m = tid; m < 3136; m += 256) {
                uint4 v = p[m];
                chunk[m] = bf16lo(v.x) + bf16hi(v.x) + bf16lo(v.y) + bf16hi(v.y)
                         + bf16lo(v.z) + bf16hi(v.z) + bf16lo(v.w) + bf16hi(v.w);
            }
            __syncthreads();
            if (tid < 49) {
                int h2 = tid / 7, w2 = tid - h2 * 7;
                #pragma unroll
                for (int d = 0; d < 2; d++)
                    for (int hh = 0; hh < 16; hh++) {
                        int row = d * 1568 + (h2 * 16 + hh) * 14 + w2 * 2;
                        s += chunk[row] + chunk[row + 1];
                    }
            }
        } else {
            const float4* p = reinterpret_cast<const float4*>((const float*)xv + base);
            for (int m = tid; m < 6272; m += 256) {
                float4 v = p[m];
                chunk[m] = v.x + v.y + v.z + v.w;
            }
            __syncthreads();
            if (tid < 49) {
                int h2 = tid / 7, w2 = tid - h2 * 7;
                #pragma unroll
                for (int d = 0; d < 2; d++)
                    for (int hh = 0; hh < 16; hh++) {
                        int row = d * 3136 + (h2 * 16 + hh) * 28 + w2 * 4;
                        s += chunk[row] + chunk[row + 1] + chunk[row + 2] + chunk[row + 3];
                    }
            }
        }
        if (tid < 49) {
            seq[(long)(t * BB + b) * INSZ + c * 49 + tid] = s * (1.0f / 512.0f);
        }
    } else if (blk < 2204) {
        // ---- tiled transpose: Wih[768][784] -> wihT[784][768] (coalesced) ---
        int blk2 = blk - 2048;
        int jt = blk2 / 13, kt = blk2 - jt * 13;
        int j0 = jt * 64, k0 = kt * 64;
        int rr = tid >> 6, c = tid & 63;
        #pragma unroll
        for (int r0 = 0; r0 < 64; r0 += 4) {
            int jL = r0 + rr;
            int k = k0 + c;
            if (k < INSZ) {
                long idx = (long)(j0 + jL) * INSZ + k;
                chunk[jL * 65 + c] = isf32 ? ((const float*)Wih)[idx]
                                           : bf16s(((const uint16_t*)Wih)[idx]);
            }
        }
        __syncthreads();
        #pragma unroll
        for (int r0 = 0; r0 < 64; r0 += 4) {
            int kL = r0 + rr;
            int k = k0 + kL;
            if (k < INSZ) {
                wihT[(long)k * 768 + j0 + c] = chunk[c * 65 + kL];
            }
        }
    } else if (blk < 2588) {
        // ---- W_hh -> packed bf16 pairs whhP[kk][768] -----------------------
        int g = (blk - 2204) * 256 + tid;     // 98304 exactly = 768*128 pairs
        int jr = g >> 7, kk = g & 127;
        uint32_t u;
        if (isf32) {
            float2 v = ((const float2*)Whh)[g];   // W[j][2kk], W[j][2kk+1]
            u = (uint32_t)f32_to_bf16_rne(v.x) | ((uint32_t)f32_to_bf16_rne(v.y) << 16);
        } else {
            u = ((const uint32_t*)Whh)[g];
        }
        whhP[kk * 768 + jr] = u;
    } else {
        // ---- gi = b_ih (bias pre-init for gi_kernel's atomicAdd) -----------
        int g = (blk - 2588) * 256 + tid;     // 98304 exactly = 128*768
        int jj = g % 768;
        float bv = isf32 ? ((const float*)bih)[jj] : bf16s(((const uint16_t*)bih)[jj]);
        gi[g] = bv;
    }
}

// ---------------------------------------------------------------------------
// gi (UNCHANGED from r1 PASS): 192 blocks = 3 j-groups x 32 tb-groups x 2 k-halves.
// Partials combined via f32 atomicAdd into bias-pre-initialized gi.
// ---------------------------------------------------------------------------
__global__ __launch_bounds__(256) void gi_kernel(const float* __restrict__ seq,
                                                 const float* __restrict__ wihT,
                                                 float* __restrict__ gi) {
    int jg = blockIdx.x % 3;
    int tbg = (blockIdx.x / 3) & 31;
    int kh = blockIdx.x / 96;                 // 0 or 1
    int tb0 = tbg * 4;
    int j = jg * 256 + threadIdx.x;
    int k0 = kh * 392;
    __shared__ __align__(16) float s_in[392 * 4];
    const float* sbase = seq + (long)tb0 * INSZ + k0;
    for (int idx = threadIdx.x; idx < 392 * 4; idx += 256) {
        int i = idx / 392, k = idx - i * 392;
        s_in[k * 4 + i] = sbase[(long)i * INSZ + k];
    }
    __syncthreads();
    float a0 = 0.0f, a1 = 0.0f, a2 = 0.0f, a3 = 0.0f;
    const float* wp = wihT + (long)k0 * 768 + j;
    const float4* s4 = reinterpret_cast<const float4*>(s_in);
    #pragma unroll 8
    for (int k = 0; k < 392; k++) {
        float w = wp[(long)k * 768];
        float4 sv = s4[k];
        a0 += w * sv.x; a1 += w * sv.y; a2 += w * sv.z; a3 += w * sv.w;
    }
    atomicAdd(&gi[(long)(tb0 + 0) * 768 + j], a0);
    atomicAdd(&gi[(long)(tb0 + 1) * 768 + j], a1);
    atomicAdd(&gi[(long)(tb0 + 2) * 768 + j], a2);
    atomicAdd(&gi[(long)(tb0 + 3) * 768 + j], a3);
}

// ---------------------------------------------------------------------------
// Sequential GRU v3: r1's PROVEN structure, but the 80 L2-streamed rows are
// hoisted into per-thread REGISTERS once (they are re-read identically all
// 16 steps). Zero global loads inside the t-loop. Countermeasures vs the
// prior session's register-residency failures: fully-unrolled kk loop
// (compile-time indices — rule #20) + __launch_bounds__(768,3) so the
// allocator budgets for the LDS-imposed 3 waves/SIMD (682 regs) instead of
// capping for higher occupancy. Summation order identical to r1 (L2-part
// first, LDS-part second) -> bit-identical absmax.
// ---------------------------------------------------------------------------
__global__ __launch_bounds__(768, 3) void gru_kernel(const float* __restrict__ gi,
                                                     const uint32_t* __restrict__ whhP,
                                                     const void* __restrict__ bhh,
                                                     const void* __restrict__ Wout,
                                                     const void* __restrict__ bout,
                                                     void* __restrict__ out,
                                                     const int* __restrict__ flag) {
    const int isf32 = *flag;
    int b = blockIdx.x;
    int j = threadIdx.x;
    __shared__ __align__(16) float h_s[HID];
    __shared__ __align__(16) float g_s[768];
    __shared__ __align__(16) uint32_t w_s[NCACHE * 768];   // 144 KB
    if (j < HID) h_s[j] = 0.0f;
    float bh = isf32 ? ((const float*)bhh)[j] : bf16s(((const uint16_t*)bhh)[j]);
    for (int idx = j; idx < NCACHE * 768; idx += 768) w_s[idx] = whhP[idx];
    const uint32_t* wpg = whhP + (long)NCACHE * 768 + j;   // rows [NCACHE,128)
    const uint32_t* wls = w_s + j;
    // hoist this thread's 80-row W slice into registers (identical every step)
    uint32_t wreg[NREG];
    #pragma unroll
    for (int kk = 0; kk < NREG; kk++) wreg[kk] = wpg[kk * 768];
    __syncthreads();
    #pragma unroll 1
    for (int t = 0; t < TT; t++) {
        float a0 = bh, a1 = 0.0f;
        const float2* h2p = reinterpret_cast<const float2*>(h_s);
        #pragma unroll
        for (int kk = 0; kk < NREG; kk++) {      // register W, LDS-broadcast h
            uint32_t u = wreg[kk];
            float2 hv = h2p[NCACHE + kk];
            a0 += bf16lo(u) * hv.x;
            a1 += bf16hi(u) * hv.y;
        }
        #pragma unroll 8
        for (int kk = 0; kk < NCACHE; kk++) {    // LDS W (2-way free pattern)
            uint32_t u = wls[kk * 768];
            float2 hv = h2p[kk];
            a0 += bf16lo(u) * hv.x;
            a1 += bf16hi(u) * hv.y;
        }
        g_s[j] = a0 + a1;
        __syncthreads();                         // g ready; dots done with h_s
        if (j < HID) {
            const float* gp = gi + (long)(t * BB + b) * 768;
            float r = 1.0f / (1.0f + __expf(-(gp[j]       + g_s[j])));
            float z = 1.0f / (1.0f + __expf(-(gp[j + 256] + g_s[j + 256])));
            float npre = gp[j + 512] + r * g_s[j + 512];
            float n = 2.0f / (1.0f + __expf(-2.0f * npre)) - 1.0f;  // tanh
            h_s[j] = (1.0f - z) * n + z * h_s[j];
        }
        __syncthreads();                         // h ready for next step
    }
    if (j < OUTN) {
        float acc = isf32 ? ((const float*)bout)[j] : bf16s(((const uint16_t*)bout)[j]);
        if (!isf32) {
            const uint4* wo = reinterpret_cast<const uint4*>((const uint16_t*)Wout + (long)j * HID);
            #pragma unroll
            for (int k = 0; k < 32; k++) {
                uint4 v = wo[k];
                const float* hp2 = &h_s[k * 8];
                acc += bf16lo(v.x) * hp2[0] + bf16hi(v.x) * hp2[1]
                     + bf16lo(v.y) * hp2[2] + bf16hi(v.y) * hp2[3]
                     + bf16lo(v.z) * hp2[4] + bf16hi(v.z) * hp2[5]
                     + bf16lo(v.w) * hp2[6] + bf16hi(v.w) * hp2[7];
            }
            ((uint16_t*)out)[b * OUTN + j] = f32_to_bf16_rne(acc);
        } else {
            const float4* wo = reinterpret_cast<const float4*>((const float*)Wout + (long)j * HID);
            #pragma unroll
            for (int k = 0; k < 64; k++) {
                float4 v = wo[k];
                const float* hp2 = &h_s[k * 4];
                acc += v.x * hp2[0] + v.y * hp2[1] + v.z * hp2[2] + v.w * hp2[3];
            }
            ((float*)out)[b * OUTN + j] = acc;
        }
    }
}

extern "C" void kernel_launch(void* const* d_in, const int* in_sizes, int n_in,
                              void* d_out, int out_size, void* d_ws, size_t ws_size,
                              hipStream_t stream) {
    const void* x    = d_in[0];  // 8*16*32*112*112
    const void* Wih  = d_in[1];  // 768*784
    const void* Whh  = d_in[2];  // 768*256
    const void* bih  = d_in[3];  // 768
    const void* bhh  = d_in[4];  // 768
    const void* Wout = d_in[5];  // 128*256
    const void* bout = d_in[6];  // 128

    char* ws = (char*)d_ws;
    float*    seq  = (float*)ws;                  // 401408 B
    float*    gi   = (float*)(ws + 401408);       // 393216 B
    float*    wihT = (float*)(ws + 1048576);      // 2408448 B  [784][768] f32
    uint32_t* whhP = (uint32_t*)(ws + 4194304);   // 393216 B   [128][768] u32
    int*     flagp = (int*)(ws + 8388608);

    detect_kernel<<<1, 256, 0, stream>>>((const uint16_t*)x, flagp);
    prep2_kernel<<<2972, 256, 0, stream>>>(x, seq, Wih, wihT, Whh, whhP, bih, gi, flagp);
    gi_kernel<<<192, 256, 0, stream>>>(seq, wihT, gi);
    gru_kernel<<<8, 768, 0, stream>>>(gi, whhP, bhh, Wout, bout, d_out, flagp);
}

// Round 6
// 389.742 us; speedup vs baseline: 1.0606x; 1.0606x over previous
//
#include <hip/hip_runtime.h>
#include <hip/hip_bf16.h>
#include <cstdint>

#define BB 8
#define CC 16
#define DD 32
#define HH 112
#define WW 112
#define TT 16        // D_OUT
#define HID 256
#define OUTN 128
#define INSZ 784     // C*7*7
#define NCACHE 48    // whhP rows pinned in LDS (48*768*4 = 144 KB; +4.3 KB state — PROVEN r1/r2/r4)
#define NTAIL (128 - NCACHE)   // 80 rows streamed from L2 each step (PROVEN r4 form)

typedef _Float16 h2v __attribute__((ext_vector_type(2)));

__device__ __forceinline__ float bf16lo(uint32_t u) { return __uint_as_float(u << 16); }
__device__ __forceinline__ float bf16hi(uint32_t u) { return __uint_as_float(u & 0xffff0000u); }
__device__ __forceinline__ float bf16s(uint16_t u)  { return __uint_as_float(((uint32_t)u) << 16); }

__device__ __forceinline__ uint16_t f32_to_bf16_rne(float f) {
    uint32_t u = __float_as_uint(f);
    return (uint16_t)((u + 0x7fffu + ((u >> 16) & 1u)) >> 16);
}

// one packed-f16 dot-2 with f32 accumulate (VALU: 1 instr vs 2 unpack + 2 fma)
__device__ __forceinline__ float dot2f(uint32_t w, uint32_t h, float acc) {
#if __has_builtin(__builtin_amdgcn_fdot2)
    return __builtin_amdgcn_fdot2(__builtin_bit_cast(h2v, w),
                                  __builtin_bit_cast(h2v, h), acc, false);
#else
    h2v wv = __builtin_bit_cast(h2v, w), hv = __builtin_bit_cast(h2v, h);
    return acc + (float)wv.x * (float)hv.x + (float)wv.y * (float)hv.y;
#endif
}

// ---------------------------------------------------------------------------
// Dtype detector (PROVEN): flag=1 -> float32, 0 -> bfloat16.
// ---------------------------------------------------------------------------
__global__ __launch_bounds__(256) void detect_kernel(const uint16_t* __restrict__ x,
                                                     int* __restrict__ flag) {
    __shared__ int cnt;
    if (threadIdx.x == 0) cnt = 0;
    __syncthreads();
    int local = 0;
    for (int i = threadIdx.x; i < 8192; i += 256) {
        uint32_t e = (x[i] >> 7) & 0xFFu;
        if (e == 0u || e >= 0x90u) local++;
    }
    atomicAdd(&cnt, local);
    __syncthreads();
    if (threadIdx.x == 0) *flag = (cnt > 400) ? 1 : 0;
}

// ---------------------------------------------------------------------------
// Pool (r1/r4 PROVEN): x -> seq (T,B,INSZ) f32, mean over 512.
// ---------------------------------------------------------------------------
__global__ __launch_bounds__(256) void pool_kernel(const void* __restrict__ xv,
                                                   float* __restrict__ seq,
                                                   const int* __restrict__ flag) {
    const int isf32 = *flag;
    int gid = blockIdx.x;                 // 2048 blocks
    int t = gid & 15, c = (gid >> 4) & 15, b = gid >> 8;
    long base = (long)(((b * CC + c) * DD) + t * 2) * (HH * WW);
    __shared__ float chunk[6272];
    int tid = threadIdx.x;
    float s = 0.0f;
    if (!isf32) {
        const uint4* p = reinterpret_cast<const uint4*>((const uint16_t*)xv + base);
        for (int m = tid; m < 3136; m += 256) {
            uint4 v = p[m];
            chunk[m] = bf16lo(v.x) + bf16hi(v.x) + bf16lo(v.y) + bf16hi(v.y)
                     + bf16lo(v.z) + bf16hi(v.z) + bf16lo(v.w) + bf16hi(v.w);
        }
        __syncthreads();
        if (tid < 49) {
            int h2 = tid / 7, w2 = tid - h2 * 7;
            #pragma unroll
            for (int d = 0; d < 2; d++)
                for (int hh = 0; hh < 16; hh++) {
                    int row = d * 1568 + (h2 * 16 + hh) * 14 + w2 * 2;
                    s += chunk[row] + chunk[row + 1];
                }
        }
    } else {
        const float4* p = reinterpret_cast<const float4*>((const float*)xv + base);
        for (int m = tid; m < 6272; m += 256) {
            float4 v = p[m];
            chunk[m] = v.x + v.y + v.z + v.w;
        }
        __syncthreads();
        if (tid < 49) {
            int h2 = tid / 7, w2 = tid - h2 * 7;
            #pragma unroll
            for (int d = 0; d < 2; d++)
                for (int hh = 0; hh < 16; hh++) {
                    int row = d * 3136 + (h2 * 16 + hh) * 28 + w2 * 4;
                    s += chunk[row] + chunk[row + 1] + chunk[row + 2] + chunk[row + 3];
                }
        }
    }
    if (tid < 49) {
        seq[(long)(t * BB + b) * INSZ + c * 49 + tid] = s * (1.0f / 512.0f);
    }
}

// ---------------------------------------------------------------------------
// pack_all (r4 PROVEN structure): LDS-tiled coalesced W_ih transpose +
// W_hh -> packed **f16** pairs (NEW: was bf16; f16 is numerically tighter
// for |w|<=1/16 and enables v_dot2_f32_f16) + gi bias init.
// blocks [0,156): wihT 64x64 tiled transpose
// blocks [156,540): whhP f16 pack (384)
// blocks [540,924): gi = b_ih init (384)
// ---------------------------------------------------------------------------
__global__ __launch_bounds__(256) void pack_all(const void* __restrict__ Wih,
                                                float* __restrict__ wihT,
                                                const void* __restrict__ Whh,
                                                uint32_t* __restrict__ whhP,
                                                const void* __restrict__ bih,
                                                float* __restrict__ gi,
                                                const int* __restrict__ flag) {
    const int isf32 = *flag;
    const int blk = blockIdx.x;
    const int tid = threadIdx.x;
    __shared__ float tlds[64][65];            // +1 pad: conflict-free both phases
    if (blk < 156) {
        int jt = blk / 13, kt = blk - jt * 13;
        int j0 = jt * 64, k0 = kt * 64;
        int rr = tid >> 6, c = tid & 63;
        #pragma unroll
        for (int r0 = 0; r0 < 64; r0 += 4) {
            int jL = r0 + rr;
            int k = k0 + c;
            if (k < INSZ) {
                long idx = (long)(j0 + jL) * INSZ + k;
                tlds[jL][c] = isf32 ? ((const float*)Wih)[idx]
                                    : bf16s(((const uint16_t*)Wih)[idx]);
            }
        }
        __syncthreads();
        #pragma unroll
        for (int r0 = 0; r0 < 64; r0 += 4) {
            int kL = r0 + rr;
            int k = k0 + kL;
            if (k < INSZ) {
                wihT[(long)k * 768 + j0 + c] = tlds[c][kL];
            }
        }
    } else if (blk < 540) {
        // ---- W_hh -> packed f16 pairs whhP[kk][768] ------------------------
        int g = (blk - 156) * 256 + tid;      // 98304 exactly = 768*128 pairs
        int jr = g >> 7, kk = g & 127;
        float lo, hi;
        if (isf32) {
            float2 v = ((const float2*)Whh)[g];   // W[j][2kk], W[j][2kk+1]
            lo = v.x; hi = v.y;
        } else {
            uint32_t raw = ((const uint32_t*)Whh)[g];
            lo = bf16lo(raw); hi = bf16hi(raw);
        }
        _Float16 flo = (_Float16)lo, fhi = (_Float16)hi;
        uint32_t u = (uint32_t)__builtin_bit_cast(uint16_t, flo)
                   | ((uint32_t)__builtin_bit_cast(uint16_t, fhi) << 16);
        whhP[kk * 768 + jr] = u;
    } else {
        // ---- gi = b_ih (bias pre-init for gi_kernel's atomicAdd) -----------
        int g = (blk - 540) * 256 + tid;      // 98304 exactly = 128*768
        int jj = g % 768;
        float bv = isf32 ? ((const float*)bih)[jj] : bf16s(((const uint16_t*)bih)[jj]);
        gi[g] = bv;
    }
}

// ---------------------------------------------------------------------------
// gi (UNCHANGED, PROVEN): 192 blocks = 3 j-groups x 32 tb-groups x 2 k-halves.
// ---------------------------------------------------------------------------
__global__ __launch_bounds__(256) void gi_kernel(const float* __restrict__ seq,
                                                 const float* __restrict__ wihT,
                                                 float* __restrict__ gi) {
    int jg = blockIdx.x % 3;
    int tbg = (blockIdx.x / 3) & 31;
    int kh = blockIdx.x / 96;                 // 0 or 1
    int tb0 = tbg * 4;
    int j = jg * 256 + threadIdx.x;
    int k0 = kh * 392;
    __shared__ __align__(16) float s_in[392 * 4];
    const float* sbase = seq + (long)tb0 * INSZ + k0;
    for (int idx = threadIdx.x; idx < 392 * 4; idx += 256) {
        int i = idx / 392, k = idx - i * 392;
        s_in[k * 4 + i] = sbase[(long)i * INSZ + k];
    }
    __syncthreads();
    float a0 = 0.0f, a1 = 0.0f, a2 = 0.0f, a3 = 0.0f;
    const float* wp = wihT + (long)k0 * 768 + j;
    const float4* s4 = reinterpret_cast<const float4*>(s_in);
    #pragma unroll 8
    for (int k = 0; k < 392; k++) {
        float w = wp[(long)k * 768];
        float4 sv = s4[k];
        a0 += w * sv.x; a1 += w * sv.y; a2 += w * sv.z; a3 += w * sv.w;
    }
    atomicAdd(&gi[(long)(tb0 + 0) * 768 + j], a0);
    atomicAdd(&gi[(long)(tb0 + 1) * 768 + j], a1);
    atomicAdd(&gi[(long)(tb0 + 2) * 768 + j], a2);
    atomicAdd(&gi[(long)(tb0 + 3) * 768 + j], a3);
}

// ---------------------------------------------------------------------------
// Sequential GRU v4: r4's PROVEN structure (48-row LDS pin + 80-row L2
// stream, rolled loops, NO register residency) with the inner op upgraded
// to v_dot2_f32_f16: W pairs are f16, and a 512 B packed-f16 mirror of h
// feeds the dot's second operand. 1 VALU instr/iter vs 5. Two alternating
// accumulators break the dependent dot chain.
// ---------------------------------------------------------------------------
__global__ __launch_bounds__(768) void gru_kernel(const float* __restrict__ gi,
                                                  const uint32_t* __restrict__ whhP,
                                                  const void* __restrict__ bhh,
                                                  const void* __restrict__ Wout,
                                                  const void* __restrict__ bout,
                                                  void* __restrict__ out,
                                                  const int* __restrict__ flag) {
    const int isf32 = *flag;
    int b = blockIdx.x;
    int j = threadIdx.x;
    __shared__ __align__(16) float h_s[HID];          // f32 h (exact, for z*h term)
    __shared__ __align__(16) uint32_t hp_s[HID / 2];  // packed-f16 mirror (512 B)
    __shared__ __align__(16) float g_s[768];
    __shared__ __align__(16) uint32_t w_s[NCACHE * 768];   // 144 KB
    if (j < HID) h_s[j] = 0.0f;
    if (j < HID / 2) hp_s[j] = 0u;
    float bh = isf32 ? ((const float*)bhh)[j] : bf16s(((const uint16_t*)bhh)[j]);
    for (int idx = j; idx < NCACHE * 768; idx += 768) w_s[idx] = whhP[idx];
    const uint32_t* wpg = whhP + (long)NCACHE * 768 + j;   // L2-resident tail rows
    const uint32_t* wls = w_s + j;
    __syncthreads();
    #pragma unroll 1
    for (int t = 0; t < TT; t++) {
        float a0 = bh, a1 = 0.0f;
        // L2 tail first (loads in flight while LDS part computes) — r4 order
        #pragma unroll 8
        for (int kk = 0; kk < NTAIL; kk += 2) {
            a0 = dot2f(wpg[kk * 768],       hp_s[NCACHE + kk],     a0);
            a1 = dot2f(wpg[(kk + 1) * 768], hp_s[NCACHE + kk + 1], a1);
        }
        #pragma unroll 8
        for (int kk = 0; kk < NCACHE; kk += 2) {
            a0 = dot2f(wls[kk * 768],       hp_s[kk],     a0);
            a1 = dot2f(wls[(kk + 1) * 768], hp_s[kk + 1], a1);
        }
        g_s[j] = a0 + a1;
        __syncthreads();                         // g ready; dots done with h state
        if (j < HID) {
            const float* gp = gi + (long)(t * BB + b) * 768;
            float r = 1.0f / (1.0f + __expf(-(gp[j]       + g_s[j])));
            float z = 1.0f / (1.0f + __expf(-(gp[j + 256] + g_s[j + 256])));
            float npre = gp[j + 512] + r * g_s[j + 512];
            float n = 2.0f / (1.0f + __expf(-2.0f * npre)) - 1.0f;  // tanh
            float hn = (1.0f - z) * n + z * h_s[j];
            h_s[j] = hn;
            ((_Float16*)hp_s)[j] = (_Float16)hn;  // 2B store, 2 lanes/bank = free
        }
        __syncthreads();                         // h ready for next step
    }
    if (j < OUTN) {
        float acc = isf32 ? ((const float*)bout)[j] : bf16s(((const uint16_t*)bout)[j]);
        if (!isf32) {
            const uint4* wo = reinterpret_cast<const uint4*>((const uint16_t*)Wout + (long)j * HID);
            #pragma unroll
            for (int k = 0; k < 32; k++) {
                uint4 v = wo[k];
                const float* hp2 = &h_s[k * 8];
                acc += bf16lo(v.x) * hp2[0] + bf16hi(v.x) * hp2[1]
                     + bf16lo(v.y) * hp2[2] + bf16hi(v.y) * hp2[3]
                     + bf16lo(v.z) * hp2[4] + bf16hi(v.z) * hp2[5]
                     + bf16lo(v.w) * hp2[6] + bf16hi(v.w) * hp2[7];
            }
            ((uint16_t*)out)[b * OUTN + j] = f32_to_bf16_rne(acc);
        } else {
            const float4* wo = reinterpret_cast<const float4*>((const float*)Wout + (long)j * HID);
            #pragma unroll
            for (int k = 0; k < 64; k++) {
                float4 v = wo[k];
                const float* hp2 = &h_s[k * 4];
                acc += v.x * hp2[0] + v.y * hp2[1] + v.z * hp2[2] + v.w * hp2[3];
            }
            ((float*)out)[b * OUTN + j] = acc;
        }
    }
}

extern "C" void kernel_launch(void* const* d_in, const int* in_sizes, int n_in,
                              void* d_out, int out_size, void* d_ws, size_t ws_size,
                              hipStream_t stream) {
    const void* x    = d_in[0];  // 8*16*32*112*112
    const void* Wih  = d_in[1];  // 768*784
    const void* Whh  = d_in[2];  // 768*256
    const void* bih  = d_in[3];  // 768
    const void* bhh  = d_in[4];  // 768
    const void* Wout = d_in[5];  // 128*256
    const void* bout = d_in[6];  // 128

    char* ws = (char*)d_ws;
    float*    seq  = (float*)ws;                  // 401408 B
    float*    gi   = (float*)(ws + 401408);       // 393216 B
    float*    wihT = (float*)(ws + 1048576);      // 2408448 B  [784][768] f32
    uint32_t* whhP = (uint32_t*)(ws + 4194304);   // 393216 B   [128][768] u32 (f16 pairs)
    int*     flagp = (int*)(ws + 8388608);

    detect_kernel<<<1, 256, 0, stream>>>((const uint16_t*)x, flagp);
    pool_kernel<<<2048, 256, 0, stream>>>(x, seq, flagp);
    pack_all<<<924, 256, 0, stream>>>(Wih, wihT, Whh, whhP, bih, gi, flagp);
    gi_kernel<<<192, 256, 0, stream>>>(seq, wihT, gi);
    gru_kernel<<<8, 768, 0, stream>>>(gi, whhP, bhh, Wout, bout, d_out, flagp);
}

// Round 7
// 381.863 us; speedup vs baseline: 1.0825x; 1.0206x over previous
//
#include <hip/hip_runtime.h>
#include <hip/hip_bf16.h>
#include <cstdint>

#define BB 8
#define CC 16
#define DD 32
#define HH 112
#define WW 112
#define TT 16        // D_OUT
#define HID 256
#define OUTN 128
#define INSZ 784     // C*7*7
#define NCACHE 48    // whhP rows pinned in LDS (48*768*4 = 144 KB — PROVEN r1/r2/r4/r6)
#define NTAIL (128 - NCACHE)   // 80 rows streamed from L2 each step (PROVEN r4/r6 form)

typedef _Float16 h2v __attribute__((ext_vector_type(2)));

__device__ __forceinline__ float bf16lo(uint32_t u) { return __uint_as_float(u << 16); }
__device__ __forceinline__ float bf16hi(uint32_t u) { return __uint_as_float(u & 0xffff0000u); }
__device__ __forceinline__ float bf16s(uint16_t u)  { return __uint_as_float(((uint32_t)u) << 16); }

__device__ __forceinline__ uint16_t f32_to_bf16_rne(float f) {
    uint32_t u = __float_as_uint(f);
    return (uint16_t)((u + 0x7fffu + ((u >> 16) & 1u)) >> 16);
}

// one packed-f16 dot-2 with f32 accumulate (PROVEN r6: the −16 µs win)
__device__ __forceinline__ float dot2f(uint32_t w, uint32_t h, float acc) {
#if __has_builtin(__builtin_amdgcn_fdot2)
    return __builtin_amdgcn_fdot2(__builtin_bit_cast(h2v, w),
                                  __builtin_bit_cast(h2v, h), acc, false);
#else
    h2v wv = __builtin_bit_cast(h2v, w), hv = __builtin_bit_cast(h2v, h);
    return acc + (float)wv.x * (float)hv.x + (float)wv.y * (float)hv.y;
#endif
}

// per-thread outlier-exponent count over one uint4 (8 bf16-interpreted values)
__device__ __forceinline__ int probe_count(uint4 v) {
    int local = 0;
    uint32_t w[4] = {v.x, v.y, v.z, v.w};
    #pragma unroll
    for (int q = 0; q < 4; q++) {
        uint32_t e0 = (w[q] >> 7)  & 0xFFu;
        uint32_t e1 = (w[q] >> 23) & 0xFFu;
        if (e0 == 0u || e0 >= 0x90u) local++;
        if (e1 == 0u || e1 >= 0x90u) local++;
    }
    return local;
}

// ---------------------------------------------------------------------------
// Pool with SELF-DETECT (replaces the separate detect launch): each block
// probes 4 KB at its own bf16-offset region (in-bounds for both dtypes;
// L1-hot re-read in the bf16 case). 2048 samples, threshold >100 (scaled
// from the PROVEN 400/8192): f32 data ~450 hits, bf16 N(0,1) ~0.
// ---------------------------------------------------------------------------
__global__ __launch_bounds__(256) void pool_kernel(const void* __restrict__ xv,
                                                   float* __restrict__ seq) {
    __shared__ float chunk[6272];
    __shared__ int cnt;
    const int tid = threadIdx.x;
    int gid = blockIdx.x;                 // 2048 blocks
    int t = gid & 15, c = (gid >> 4) & 15, b = gid >> 8;
    long base = (long)(((b * CC + c) * DD) + t * 2) * (HH * WW);
    if (tid == 0) cnt = 0;
    __syncthreads();
    {
        const uint4* probe = reinterpret_cast<const uint4*>((const uint16_t*)xv + base);
        atomicAdd(&cnt, probe_count(probe[tid]));
    }
    __syncthreads();
    const int isf32 = (cnt > 100) ? 1 : 0;
    float s = 0.0f;
    if (!isf32) {
        const uint4* p = reinterpret_cast<const uint4*>((const uint16_t*)xv + base);
        for (int m = tid; m < 3136; m += 256) {
            uint4 v = p[m];
            chunk[m] = bf16lo(v.x) + bf16hi(v.x) + bf16lo(v.y) + bf16hi(v.y)
                     + bf16lo(v.z) + bf16hi(v.z) + bf16lo(v.w) + bf16hi(v.w);
        }
        __syncthreads();
        if (tid < 49) {
            int h2 = tid / 7, w2 = tid - h2 * 7;
            #pragma unroll
            for (int d = 0; d < 2; d++)
                for (int hh = 0; hh < 16; hh++) {
                    int row = d * 1568 + (h2 * 16 + hh) * 14 + w2 * 2;
                    s += chunk[row] + chunk[row + 1];
                }
        }
    } else {
        const float4* p = reinterpret_cast<const float4*>((const float*)xv + base);
        for (int m = tid; m < 6272; m += 256) {
            float4 v = p[m];
            chunk[m] = v.x + v.y + v.z + v.w;
        }
        __syncthreads();
        if (tid < 49) {
            int h2 = tid / 7, w2 = tid - h2 * 7;
            #pragma unroll
            for (int d = 0; d < 2; d++)
                for (int hh = 0; hh < 16; hh++) {
                    int row = d * 3136 + (h2 * 16 + hh) * 28 + w2 * 4;
                    s += chunk[row] + chunk[row + 1] + chunk[row + 2] + chunk[row + 3];
                }
        }
    }
    if (tid < 49) {
        seq[(long)(t * BB + b) * INSZ + c * 49 + tid] = s * (1.0f / 512.0f);
    }
}

// ---------------------------------------------------------------------------
// pack_all with SELF-DETECT from Whh's first 4 KB (same statistics: f16/bf16
// weights in ±1/16 give ~0 hits; f32 low-halves give ~450). Block 0 publishes
// the flag for gru (stream-ordered: gru launches 2 dispatches later).
// blocks [0,156): wihT 64x64 tiled coalesced transpose (PROVEN r4)
// blocks [156,540): whhP f16 pack (PROVEN r6)
// blocks [540,924): gi = b_ih init (PROVEN r1)
// ---------------------------------------------------------------------------
__global__ __launch_bounds__(256) void pack_all(const void* __restrict__ Wih,
                                                float* __restrict__ wihT,
                                                const void* __restrict__ Whh,
                                                uint32_t* __restrict__ whhP,
                                                const void* __restrict__ bih,
                                                float* __restrict__ gi,
                                                int* __restrict__ flagp) {
    const int blk = blockIdx.x;
    const int tid = threadIdx.x;
    __shared__ float tlds[64][65];
    __shared__ int cnt;
    if (tid == 0) cnt = 0;
    __syncthreads();
    {
        const uint4* probe = reinterpret_cast<const uint4*>(Whh);
        atomicAdd(&cnt, probe_count(probe[tid]));
    }
    __syncthreads();
    const int isf32 = (cnt > 100) ? 1 : 0;
    if (blk == 0 && tid == 0) *flagp = isf32;     // for gru (stream-ordered)

    if (blk < 156) {
        int jt = blk / 13, kt = blk - jt * 13;
        int j0 = jt * 64, k0 = kt * 64;
        int rr = tid >> 6, c = tid & 63;
        #pragma unroll
        for (int r0 = 0; r0 < 64; r0 += 4) {
            int jL = r0 + rr;
            int k = k0 + c;
            if (k < INSZ) {
                long idx = (long)(j0 + jL) * INSZ + k;
                tlds[jL][c] = isf32 ? ((const float*)Wih)[idx]
                                    : bf16s(((const uint16_t*)Wih)[idx]);
            }
        }
        __syncthreads();
        #pragma unroll
        for (int r0 = 0; r0 < 64; r0 += 4) {
            int kL = r0 + rr;
            int k = k0 + kL;
            if (k < INSZ) {
                wihT[(long)k * 768 + j0 + c] = tlds[c][kL];
            }
        }
    } else if (blk < 540) {
        // ---- W_hh -> packed f16 pairs whhP[kk][768] ------------------------
        int g = (blk - 156) * 256 + tid;      // 98304 exactly = 768*128 pairs
        int jr = g >> 7, kk = g & 127;
        float lo, hi;
        if (isf32) {
            float2 v = ((const float2*)Whh)[g];   // W[j][2kk], W[j][2kk+1]
            lo = v.x; hi = v.y;
        } else {
            uint32_t raw = ((const uint32_t*)Whh)[g];
            lo = bf16lo(raw); hi = bf16hi(raw);
        }
        _Float16 flo = (_Float16)lo, fhi = (_Float16)hi;
        uint32_t u = (uint32_t)__builtin_bit_cast(uint16_t, flo)
                   | ((uint32_t)__builtin_bit_cast(uint16_t, fhi) << 16);
        whhP[kk * 768 + jr] = u;
    } else {
        // ---- gi = b_ih (bias pre-init for gi_kernel's atomicAdd) -----------
        int g = (blk - 540) * 256 + tid;      // 98304 exactly = 128*768
        int jj = g % 768;
        float bv = isf32 ? ((const float*)bih)[jj] : bf16s(((const uint16_t*)bih)[jj]);
        gi[g] = bv;
    }
}

// ---------------------------------------------------------------------------
// gi (UNCHANGED, PROVEN): 192 blocks = 3 j-groups x 32 tb-groups x 2 k-halves.
// ---------------------------------------------------------------------------
__global__ __launch_bounds__(256) void gi_kernel(const float* __restrict__ seq,
                                                 const float* __restrict__ wihT,
                                                 float* __restrict__ gi) {
    int jg = blockIdx.x % 3;
    int tbg = (blockIdx.x / 3) & 31;
    int kh = blockIdx.x / 96;                 // 0 or 1
    int tb0 = tbg * 4;
    int j = jg * 256 + threadIdx.x;
    int k0 = kh * 392;
    __shared__ __align__(16) float s_in[392 * 4];
    const float* sbase = seq + (long)tb0 * INSZ + k0;
    for (int idx = threadIdx.x; idx < 392 * 4; idx += 256) {
        int i = idx / 392, k = idx - i * 392;
        s_in[k * 4 + i] = sbase[(long)i * INSZ + k];
    }
    __syncthreads();
    float a0 = 0.0f, a1 = 0.0f, a2 = 0.0f, a3 = 0.0f;
    const float* wp = wihT + (long)k0 * 768 + j;
    const float4* s4 = reinterpret_cast<const float4*>(s_in);
    #pragma unroll 8
    for (int k = 0; k < 392; k++) {
        float w = wp[(long)k * 768];
        float4 sv = s4[k];
        a0 += w * sv.x; a1 += w * sv.y; a2 += w * sv.z; a3 += w * sv.w;
    }
    atomicAdd(&gi[(long)(tb0 + 0) * 768 + j], a0);
    atomicAdd(&gi[(long)(tb0 + 1) * 768 + j], a1);
    atomicAdd(&gi[(long)(tb0 + 2) * 768 + j], a2);
    atomicAdd(&gi[(long)(tb0 + 3) * 768 + j], a3);
}

// ---------------------------------------------------------------------------
// Sequential GRU v5: r6's PROVEN fdot2 structure with the h-mirror reads
// vectorized to uint4 (4 packed pairs per ds_read_b128 broadcast) — LDS-read
// instrs per step: 128 -> 32. Summation order preserved EXACTLY (even kk ->
// a0, odd -> a1, ascending; tail then LDS part) -> bit-identical absmax.
// Prologue LDS copy vectorized to uint4 (36864 -> 9216 instrs).
// ---------------------------------------------------------------------------
__global__ __launch_bounds__(768) void gru_kernel(const float* __restrict__ gi,
                                                  const uint32_t* __restrict__ whhP,
                                                  const void* __restrict__ bhh,
                                                  const void* __restrict__ Wout,
                                                  const void* __restrict__ bout,
                                                  void* __restrict__ out,
                                                  const int* __restrict__ flag) {
    const int isf32 = *flag;
    int b = blockIdx.x;
    int j = threadIdx.x;
    __shared__ __align__(16) float h_s[HID];          // f32 h (exact, for z*h term)
    __shared__ __align__(16) uint32_t hp_s[HID / 2];  // packed-f16 mirror (512 B)
    __shared__ __align__(16) float g_s[768];
    __shared__ __align__(16) uint32_t w_s[NCACHE * 768];   // 144 KB
    if (j < HID) h_s[j] = 0.0f;
    if (j < HID / 2) hp_s[j] = 0u;
    float bh = isf32 ? ((const float*)bhh)[j] : bf16s(((const uint16_t*)bhh)[j]);
    {   // vectorized prologue copy: rows [0,NCACHE) -> LDS
        const uint4* src4 = reinterpret_cast<const uint4*>(whhP);
        uint4* dst4 = reinterpret_cast<uint4*>(w_s);
        for (int idx = j; idx < NCACHE * 192; idx += 768) dst4[idx] = src4[idx];
    }
    const uint32_t* wpg = whhP + (long)NCACHE * 768 + j;   // L2-resident tail rows
    const uint32_t* wls = w_s + j;
    const uint4* hq = reinterpret_cast<const uint4*>(hp_s); // 4 pairs / read
    __syncthreads();
    #pragma unroll 1
    for (int t = 0; t < TT; t++) {
        float a0 = bh, a1 = 0.0f;
        // L2 tail first (loads in flight while LDS part computes) — r4/r6 order
        #pragma unroll 4
        for (int kk = 0; kk < NTAIL; kk += 4) {
            uint4 hv = hq[(NCACHE + kk) >> 2];
            a0 = dot2f(wpg[(kk + 0) * 768], hv.x, a0);
            a1 = dot2f(wpg[(kk + 1) * 768], hv.y, a1);
            a0 = dot2f(wpg[(kk + 2) * 768], hv.z, a0);
            a1 = dot2f(wpg[(kk + 3) * 768], hv.w, a1);
        }
        #pragma unroll 4
        for (int kk = 0; kk < NCACHE; kk += 4) {
            uint4 hv = hq[kk >> 2];
            a0 = dot2f(wls[(kk + 0) * 768], hv.x, a0);
            a1 = dot2f(wls[(kk + 1) * 768], hv.y, a1);
            a0 = dot2f(wls[(kk + 2) * 768], hv.z, a0);
            a1 = dot2f(wls[(kk + 3) * 768], hv.w, a1);
        }
        g_s[j] = a0 + a1;
        __syncthreads();                         // g ready; dots done with h state
        if (j < HID) {
            const float* gp = gi + (long)(t * BB + b) * 768;
            float r = 1.0f / (1.0f + __expf(-(gp[j]       + g_s[j])));
            float z = 1.0f / (1.0f + __expf(-(gp[j + 256] + g_s[j + 256])));
            float npre = gp[j + 512] + r * g_s[j + 512];
            float n = 2.0f / (1.0f + __expf(-2.0f * npre)) - 1.0f;  // tanh
            float hn = (1.0f - z) * n + z * h_s[j];
            h_s[j] = hn;
            ((_Float16*)hp_s)[j] = (_Float16)hn;  // 2B store, 2 lanes/bank = free
        }
        __syncthreads();                         // h ready for next step
    }
    if (j < OUTN) {
        float acc = isf32 ? ((const float*)bout)[j] : bf16s(((const uint16_t*)bout)[j]);
        if (!isf32) {
            const uint4* wo = reinterpret_cast<const uint4*>((const uint16_t*)Wout + (long)j * HID);
            #pragma unroll
            for (int k = 0; k < 32; k++) {
                uint4 v = wo[k];
                const float* hp2 = &h_s[k * 8];
                acc += bf16lo(v.x) * hp2[0] + bf16hi(v.x) * hp2[1]
                     + bf16lo(v.y) * hp2[2] + bf16hi(v.y) * hp2[3]
                     + bf16lo(v.z) * hp2[4] + bf16hi(v.z) * hp2[5]
                     + bf16lo(v.w) * hp2[6] + bf16hi(v.w) * hp2[7];
            }
            ((uint16_t*)out)[b * OUTN + j] = f32_to_bf16_rne(acc);
        } else {
            const float4* wo = reinterpret_cast<const float4*>((const float*)Wout + (long)j * HID);
            #pragma unroll
            for (int k = 0; k < 64; k++) {
                float4 v = wo[k];
                const float* hp2 = &h_s[k * 4];
                acc += v.x * hp2[0] + v.y * hp2[1] + v.z * hp2[2] + v.w * hp2[3];
            }
            ((float*)out)[b * OUTN + j] = acc;
        }
    }
}

extern "C" void kernel_launch(void* const* d_in, const int* in_sizes, int n_in,
                              void* d_out, int out_size, void* d_ws, size_t ws_size,
                              hipStream_t stream) {
    const void* x    = d_in[0];  // 8*16*32*112*112
    const void* Wih  = d_in[1];  // 768*784
    const void* Whh  = d_in[2];  // 768*256
    const void* bih  = d_in[3];  // 768
    const void* bhh  = d_in[4];  // 768
    const void* Wout = d_in[5];  // 128*256
    const void* bout = d_in[6];  // 128

    char* ws = (char*)d_ws;
    float*    seq  = (float*)ws;                  // 401408 B
    float*    gi   = (float*)(ws + 401408);       // 393216 B
    float*    wihT = (float*)(ws + 1048576);      // 2408448 B  [784][768] f32
    uint32_t* whhP = (uint32_t*)(ws + 4194304);   // 393216 B   [128][768] u32 (f16 pairs)
    int*     flagp = (int*)(ws + 8388608);

    pool_kernel<<<2048, 256, 0, stream>>>(x, seq);
    pack_all<<<924, 256, 0, stream>>>(Wih, wihT, Whh, whhP, bih, gi, flagp);
    gi_kernel<<<192, 256, 0, stream>>>(seq, wihT, gi);
    gru_kernel<<<8, 768, 0, stream>>>(gi, whhP, bhh, Wout, bout, d_out, flagp);
}